// Round 12
// baseline (53.923 us; speedup 1.0000x reference)
//
#include <hip/hip_runtime.h>
#include <hip/hip_bf16.h>

// Problem constants
#define BATCH 32768
#define NIN   256
#define NOUT  256
// degrees 1..8 via MFMA; degree 0 (T_0 = 1) folded into per-column bias

typedef __attribute__((ext_vector_type(8))) short bf16x8;
typedef __attribute__((ext_vector_type(4))) float f32x4;
typedef __attribute__((ext_vector_type(2))) float f32x2;
typedef __attribute__((ext_vector_type(4))) unsigned int u32x4;

static __device__ __forceinline__ unsigned short bf16_rne(float f) {
  unsigned u = __float_as_uint(f);
  u += 0x7fffu + ((u >> 16) & 1u);
  return (unsigned short)(u >> 16);
}

// fast tanh: t = sign(v) * (1 - z) / (1 + z), z = exp(-2|v|)
static __device__ __forceinline__ float fast_tanh(float v) {
  float a = fabsf(v);
  float z = __expf(-2.0f * a);
  float r = (1.0f - z) * __builtin_amdgcn_rcpf(1.0f + z);
  return copysignf(r, v);
}

static __device__ __forceinline__ unsigned pack_pair(f32x2 v) {
  __hip_bfloat162 h2 = __float22bfloat162_rn(make_float2(v[0], v[1]));
  union { __hip_bfloat162 h; unsigned u; } cv;
  cv.h = h2;
  return cv.u;
}

static __device__ __forceinline__ void init_state(const f32x4 x0, const f32x4 x1,
                                                  f32x2* cur, f32x2* prev,
                                                  f32x2* t2) {
  #pragma unroll
  for (int p = 0; p < 4; ++p) {
    float va = (p < 2) ? x0[2 * p]     : x1[2 * p - 4];
    float vb = (p < 2) ? x0[2 * p + 1] : x1[2 * p - 3];
    float ta = fast_tanh(va);
    float tb = fast_tanh(vb);
    cur[p]  = (f32x2){ta, tb};        // T_1
    t2[p]   = cur[p] + cur[p];
    prev[p] = (f32x2){1.0f, 1.0f};    // T_0
  }
}

// write bf16(T_{dm+1}) to A slot dm, then advance the recurrence (if dm<7)
static __device__ __forceinline__ void basis_slice(char* awr, int dm,
                                                   f32x2* cur, f32x2* prev,
                                                   f32x2* t2) {
  u32x4 pk;
  #pragma unroll
  for (int q = 0; q < 4; ++q) pk[q] = pack_pair(cur[q]);
  *(u32x4*)(awr + dm * 8192) = pk;              // ds_write_b128, conflict-free
  if (dm < 7) {
    #pragma unroll
    for (int q = 0; q < 4; ++q) {
      f32x2 nx = __builtin_elementwise_fma(t2[q], cur[q], -prev[q]);
      prev[q] = cur[q];
      cur[q]  = nx;
    }
  }
}

// async global->LDS, 16B per lane, LDS dest = wave-uniform base + lane*16
static __device__ __forceinline__ void gload_lds16(const void* g, void* l) {
  __builtin_amdgcn_global_load_lds(
      (const __attribute__((address_space(1))) unsigned int*)g,
      (__attribute__((address_space(3))) unsigned int*)l, 16, 0, 0);
}

// ---------------------------------------------------------------------------
// Prepack into DMA-chunk layout:
// chunk (ic, ph) = 32KB at offset (ic*4+ph)*32768 bytes; inside the chunk,
// element (dd, tile, kg, col, j) at (dd*16+tile)*512 + kg*128 + col*8 + j
//   value = bf16( c_basis[n][i][dm+1] * c_act[n][i] ),
//   n = tile*16+col,  i = ic*32+kg*8+j,  dm = ph*2+dd.
// tid bits: j:0-2 col:3-6 kg:7-8 tile:9-12 dd:13 ph:14-15 ic:16-18.
// ---------------------------------------------------------------------------
__global__ void cheby_prepack(const float* __restrict__ cb,
                              const float* __restrict__ ca,
                              unsigned short* __restrict__ Bp) {
  int tid = blockIdx.x * 256 + threadIdx.x;
  int j    = tid & 7;
  int col  = (tid >> 3) & 15;
  int kg   = (tid >> 7) & 3;
  int tile = (tid >> 9) & 15;
  int dd   = (tid >> 13) & 1;
  int ph   = (tid >> 14) & 3;
  int ic   = (tid >> 16) & 7;
  int i  = ic * 32 + kg * 8 + j;
  int n  = tile * 16 + col;
  int dm = ph * 2 + dd;
  float w = cb[n * (NIN * 9) + i * 9 + (dm + 1)] * ca[n * NIN + i];
  Bp[tid] = bf16_rne(w);
}

// bias[n] = sum_i c_basis[n][i][0] * c_act[n][i]   (T_0 == 1 term)
__global__ void cheby_bias(const float* __restrict__ cb,
                           const float* __restrict__ ca,
                           float* __restrict__ bias) {
  int n = blockIdx.x;
  int l = threadIdx.x;            // 64 threads = one wave
  float s = 0.0f;
  #pragma unroll
  for (int k = 0; k < 4; ++k) {
    int i = l + k * 64;
    s += cb[n * (NIN * 9) + i * 9] * ca[n * NIN + i];
  }
  #pragma unroll
  for (int off = 32; off; off >>= 1) s += __shfl_down(s, off);
  if (l == 0) bias[n] = s;
}

// ---------------------------------------------------------------------------
// Fused cheby + GEMM: A in LDS (single-buffered, slot-rotated), B DMA-staged
// through LDS (2-half ring), 32 MFMA per phase, 32 phases.
// Grid: 256 blocks x 512 threads (8 waves), 1 block/CU, LDS 128KB.
// Block tile: 128 rows x 256 cols; wave tile 64x64 (wr=w>>2, wc=w&3).
// Phase (ic, ph):
//   [x prefetch (ph0) | DMA-stage B chunk g+1 into ring half (ph+1)&1 |
//    ds_read A slots {2ph,2ph+1} + B half ph&1 | 2 basis slices]
//   -> s_waitcnt vmcnt(0) lgkmcnt(0); s_barrier -> 32 MFMA.
// A slot rotation: reads {2ph,2ph+1}; writes {ph0: 6,7 of basis(ic);
// ph1..3: 2(ph-1),2(ph-1)+1 of basis(ic+1)} -- disjoint from same-phase
// reads, >=1 barrier between any write and its read.  Per-CU B traffic
// from L2: 1MB via DMA (was 2MB via per-wave VGPR loads); vmem path freed.
// ---------------------------------------------------------------------------
__global__ __launch_bounds__(512, 2)
void cheby_mfma(const float* __restrict__ x,
                const unsigned short* __restrict__ Bp,
                const float* __restrict__ bias,
                float* __restrict__ out) {
  __shared__ unsigned short As[8][8][512];    // 64 KB [slot][plane][frag]
  __shared__ unsigned short Bs[2][32][512];   // 64 KB [half][dd*16+tile][frag]

  int tid  = threadIdx.x;
  int w    = tid >> 6;            // 0..7
  int lane = tid & 63;
  int row16 = lane & 15;          // A row / B col / C-D col
  int kg    = lane >> 4;          // k-group 0..3

  int wr = w >> 2;                // row half (0..1)
  int wc = w & 3;                 // col strip (0..3)
  int base_row = blockIdx.x * 128;
  int tile0    = wc * 4;          // wave's 4 column tiles (64 cols)

  // basis writer: wave w owns plane w
  const float* xw = x + (size_t)(base_row + w * 16 + row16) * NIN + kg * 8;
  char* awr = (char*)As + w * 1024 + lane * 16;          // + slot*8192
  // readers
  const char* ard = (const char*)As + (wr * 4) * 1024 + lane * 16;
  const char* brd = (const char*)Bs + kg * 256 + row16 * 16;
  // DMA stage lanes (linear, wave-uniform base + lane*16)
  const char* bsrc = (const char*)Bp + tid * 16;         // + chunk*32768 + r*8192
  char*       bdst = (char*)Bs + tid * 16;               // + half*32768 + r*8192

  f32x4 acc[4][4];
  #pragma unroll
  for (int a = 0; a < 4; ++a)
    #pragma unroll
    for (int b = 0; b < 4; ++b) acc[a][b] = (f32x4)0.0f;

  // ---- prologue ----
  f32x4 xa = *(const f32x4*)xw;
  f32x4 xb = *(const f32x4*)(xw + 4);
  // stage B chunk 0 -> ring half 0
  #pragma unroll
  for (int r = 0; r < 4; ++r) gload_lds16(bsrc + r * 8192, bdst + r * 8192);
  // basis(0): slots 0..5 (T_1..T_6); state exits as T_7
  f32x2 cur[4], prev[4], t2[4];
  init_state(xa, xb, cur, prev, t2);
  #pragma unroll
  for (int dm = 0; dm < 6; ++dm) basis_slice(awr, dm, cur, prev, t2);
  __builtin_amdgcn_sched_barrier(0);
  asm volatile("s_waitcnt vmcnt(0) lgkmcnt(0)" ::: "memory");
  __builtin_amdgcn_s_barrier();
  __builtin_amdgcn_sched_barrier(0);

  // ---- main loop: 8 ic x 4 phases ----
  for (int ic = 0; ic < 8; ++ic) {
    const char* chunk_src = bsrc + (size_t)(ic * 4) * 32768;
    #pragma unroll
    for (int ph = 0; ph < 4; ++ph) {
      const bool last = (ic == 7) && (ph == 3);
      // x prefetch for next ic (consumed at ph1's init_state)
      if (ph == 0 && ic < 7) {
        xa = *(const f32x4*)(xw + (ic + 1) * 32);
        xb = *(const f32x4*)(xw + (ic + 1) * 32 + 4);
      }
      // DMA-stage chunk g+1 into ring half (ph+1)&1 (full phase of cover)
      if (!last) {
        const char* s  = chunk_src + (size_t)(ph + 1) * 32768;
        char*       d0 = bdst + ((ph + 1) & 1) * 32768;
        #pragma unroll
        for (int r = 0; r < 4; ++r)
          gload_lds16(s + r * 8192, d0 + r * 8192);
      }
      // A fragments: slots 2ph, 2ph+1
      bf16x8 af[2][4];
      #pragma unroll
      for (int dd = 0; dd < 2; ++dd)
        #pragma unroll
        for (int mt = 0; mt < 4; ++mt)
          af[dd][mt] =
              *(const bf16x8*)(ard + (2 * ph + dd) * 8192 + mt * 1024);
      // B fragments: ring half ph&1
      bf16x8 bfr[2][4];
      #pragma unroll
      for (int dd = 0; dd < 2; ++dd)
        #pragma unroll
        for (int nt = 0; nt < 4; ++nt)
          bfr[dd][nt] = *(const bf16x8*)(
              brd + (ph & 1) * 32768 + (dd * 16 + tile0 + nt) * 1024);
      // basis slices (slot rotation)
      if (ph == 0) {                       // finish basis(ic): slots 6,7
        basis_slice(awr, 6, cur, prev, t2);
        basis_slice(awr, 7, cur, prev, t2);
      } else if (ic < 7) {                 // basis(ic+1): slots 0..5
        if (ph == 1) init_state(xa, xb, cur, prev, t2);
        basis_slice(awr, 2 * (ph - 1),     cur, prev, t2);
        basis_slice(awr, 2 * (ph - 1) + 1, cur, prev, t2);
      }
      // phase barrier (DMA was issued a full phase ago -> cheap drain)
      if (!last) {
        __builtin_amdgcn_sched_barrier(0);
        asm volatile("s_waitcnt vmcnt(0) lgkmcnt(0)" ::: "memory");
        __builtin_amdgcn_s_barrier();
        __builtin_amdgcn_sched_barrier(0);
      }
      // 32 MFMA
      __builtin_amdgcn_s_setprio(1);
      #pragma unroll
      for (int dd = 0; dd < 2; ++dd)
        #pragma unroll
        for (int mt = 0; mt < 4; ++mt)
          #pragma unroll
          for (int nt = 0; nt < 4; ++nt)
            acc[mt][nt] = __builtin_amdgcn_mfma_f32_16x16x32_bf16(
                af[dd][mt], bfr[dd][nt], acc[mt][nt], 0, 0, 0);
      __builtin_amdgcn_s_setprio(0);
    }
  }

  // epilogue: C/D layout col = lane&15, row = (lane>>4)*4 + q  (m89/m91)
  #pragma unroll
  for (int nt = 0; nt < 4; ++nt) {
    int c = (tile0 + nt) * 16 + row16;
    float bv = bias[c];
    #pragma unroll
    for (int mt = 0; mt < 4; ++mt) {
      int r0 = base_row + wr * 64 + mt * 16 + kg * 4;
      #pragma unroll
      for (int q = 0; q < 4; ++q)
        out[(size_t)(r0 + q) * NOUT + c] = acc[mt][nt][q] + bv;
    }
  }
}

extern "C" void kernel_launch(void* const* d_in, const int* in_sizes, int n_in,
                              void* d_out, int out_size, void* d_ws, size_t ws_size,
                              hipStream_t stream) {
  const float* x  = (const float*)d_in[0];
  const float* cb = (const float*)d_in[1];   // c_basis (256,256,9)
  const float* ca = (const float*)d_in[2];   // c_act   (256,256)
  float* out = (float*)d_out;

  unsigned short* Bp = (unsigned short*)d_ws;                    // 1 MB
  float* bias = (float*)((char*)d_ws + 8 * NIN * NOUT * 2);      // 1 KB

  cheby_prepack<<<(8 * NIN * NOUT) / 256, 256, 0, stream>>>(cb, ca, Bp);
  cheby_bias<<<NOUT, 64, 0, stream>>>(cb, ca, bias);
  cheby_mfma<<<256, 512, 0, stream>>>(x, Bp, bias, out);
}

// Round 15
// 51.370 us; speedup vs baseline: 1.0497x; 1.0497x over previous
//
#include <hip/hip_runtime.h>
#include <hip/hip_bf16.h>

// Problem constants
#define BATCH 32768
#define NIN   256
#define NOUT  256
// degrees 1..8 via MFMA; degree 0 (T_0 = 1) folded into per-column bias

typedef __attribute__((ext_vector_type(8)))  short bf16x8;
typedef __attribute__((ext_vector_type(4)))  float f32x4;
typedef __attribute__((ext_vector_type(16))) float f32x16;
typedef __attribute__((ext_vector_type(2)))  float f32x2;
typedef __attribute__((ext_vector_type(4)))  unsigned int u32x4;

static __device__ __forceinline__ unsigned short bf16_rne(float f) {
  unsigned u = __float_as_uint(f);
  u += 0x7fffu + ((u >> 16) & 1u);
  return (unsigned short)(u >> 16);
}

// fast tanh: t = sign(v) * (1 - z) / (1 + z), z = exp(-2|v|)
static __device__ __forceinline__ float fast_tanh(float v) {
  float a = fabsf(v);
  float z = __expf(-2.0f * a);
  float r = (1.0f - z) * __builtin_amdgcn_rcpf(1.0f + z);
  return copysignf(r, v);
}

static __device__ __forceinline__ unsigned pack_pair(f32x2 v) {
  __hip_bfloat162 h2 = __float22bfloat162_rn(make_float2(v[0], v[1]));
  union { __hip_bfloat162 h; unsigned u; } cv;
  cv.h = h2;
  return cv.u;
}

static __device__ __forceinline__ void init_state(const f32x4 x0, const f32x4 x1,
                                                  f32x2* cur, f32x2* prev,
                                                  f32x2* t2) {
  #pragma unroll
  for (int p = 0; p < 4; ++p) {
    float va = (p < 2) ? x0[2 * p]     : x1[2 * p - 4];
    float vb = (p < 2) ? x0[2 * p + 1] : x1[2 * p - 3];
    float ta = fast_tanh(va);
    float tb = fast_tanh(vb);
    cur[p]  = (f32x2){ta, tb};        // T_1
    t2[p]   = cur[p] + cur[p];
    prev[p] = (f32x2){1.0f, 1.0f};    // T_0
  }
}

// raw barrier (no vmcnt drain) with scheduler fences
static __device__ __forceinline__ void phase_barrier() {
  __builtin_amdgcn_sched_barrier(0);
  __builtin_amdgcn_s_barrier();
  __builtin_amdgcn_sched_barrier(0);
}

// ---------------------------------------------------------------------------
// Prepack for 32x32x16 fragments:
// fragment (dm, ic, tile32, chunk) = 1KB at byte offset
//   ((dm*8+ic)*16 + tile32*2 + chunk)*1024, lane l holds 16B at l*16:
//   col = l&31, kh = l>>5, j = 0..7
//   value = bf16( c_basis[n][i][dm+1] * c_act[n][i] ),
//   n = tile32*32 + col,  i = ic*32 + chunk*16 + kh*8 + j.
// tid bits: j:0-2 fl:3-8 chunk:9 tile32:10-12 ic:13-15 dm:16-18.
// ---------------------------------------------------------------------------
__global__ void cheby_prepack(const float* __restrict__ cb,
                              const float* __restrict__ ca,
                              unsigned short* __restrict__ Bp) {
  int tid = blockIdx.x * 256 + threadIdx.x;
  int j      = tid & 7;
  int fl     = (tid >> 3) & 63;
  int chunk  = (tid >> 9) & 1;
  int tile32 = (tid >> 10) & 7;
  int ic     = (tid >> 13) & 7;
  int dm     = (tid >> 16) & 7;
  int col = fl & 31;
  int kh  = fl >> 5;
  int n = tile32 * 32 + col;
  int i = ic * 32 + chunk * 16 + kh * 8 + j;
  float w = cb[n * (NIN * 9) + i * 9 + (dm + 1)] * ca[n * NIN + i];
  Bp[tid] = bf16_rne(w);
}

// bias[n] = sum_i c_basis[n][i][0] * c_act[n][i]   (T_0 == 1 term)
__global__ void cheby_bias(const float* __restrict__ cb,
                           const float* __restrict__ ca,
                           float* __restrict__ bias) {
  int n = blockIdx.x;
  int l = threadIdx.x;
  float s = 0.0f;
  #pragma unroll
  for (int k = 0; k < 4; ++k) {
    int i = l + k * 64;
    s += cb[n * (NIN * 9) + i * 9] * ca[n * NIN + i];
  }
  #pragma unroll
  for (int off = 32; off; off >>= 1) s += __shfl_down(s, off);
  if (l == 0) bias[n] = s;
}

// ---------------------------------------------------------------------------
// Fused cheby + GEMM, 8-phase pipeline (R10 schedule), 32x32x16 MFMA.
// Grid: 256 blocks x 512 threads (8 waves), 1 block/CU, LDS 128KB.
// Block tile: 128 rows x 256 cols. Wave tile 64x64 = 2x2 tiles of 32x32,
// K=32 per degree via 2 chunks of 32x32x16 (8 MFMA/phase vs 16 before;
// rate 2382 vs 2075 TF).  A-LDS layout per (buf,d): 4 planes x 2 chunks
// x 1KB fragments; lane l of a fragment: row=l&31, kh=l>>5 (k=(kh)*8+j).
// Writer: thread t -> byte t*16 (plane=t>>7, chunk=(t>>6)&1, fl=t&63),
// x features koff=((t>>5)&3)*8 -- conflict-free contiguous ds_write_b128.
// Per phase p (8 per ic): { ds_read A(next) || 4 B-loads(next) ||
// basis slice p of ic+1 } -> s_barrier -> 8 MFMA.
// ---------------------------------------------------------------------------
__global__ __launch_bounds__(512, 2)
void cheby_mfma(const float* __restrict__ x,
                const unsigned short* __restrict__ Bp,
                const float* __restrict__ bias,
                float* __restrict__ out) {
  // [buf][d][plane 0..3][chunk 0..1][512 shorts] = 128 KB
  __shared__ unsigned short Asm_[2][8][4][2][512];

  int tid  = threadIdx.x;
  int w    = tid >> 6;            // 0..7
  int lane = tid & 63;

  int wr = w >> 2;                // row half (0..1)
  int wc = w & 3;                 // col strip (0..3), 64 cols each
  int base_row = blockIdx.x * 128;

  // writer role: thread t -> row = (t>>7)*32 + (t&31), koff = ((t>>5)&3)*8
  const float* xw = x + (size_t)(base_row + ((tid >> 7) << 5) + (tid & 31)) * NIN
                      + ((tid >> 5) & 3) * 8;
  char* wbase = (char*)Asm_ + tid * 16;                  // + d*8192 + buf*65536
  // readers
  const char* abase   = (const char*)Asm_ + lane * 16;   // + plane*2048 + chunk*1024
  const char* bp_lane = (const char*)Bp + lane * 16;

  f32x16 acc[2][2];
  #pragma unroll
  for (int a = 0; a < 2; ++a)
    #pragma unroll
    for (int b = 0; b < 2; ++b) acc[a][b] = (f32x16)0.0f;

  // ---- prologue: full basis(0) -> buf0 ----
  f32x4 xa = *(const f32x4*)xw;
  f32x4 xb = *(const f32x4*)(xw + 4);
  {
    f32x2 c0[4], p0[4], t0[4];
    init_state(xa, xb, c0, p0, t0);
    #pragma unroll
    for (int d = 0; d < 8; ++d) {
      u32x4 pk;
      #pragma unroll
      for (int q = 0; q < 4; ++q) pk[q] = pack_pair(c0[q]);
      *(u32x4*)(wbase + d * 8192) = pk;
      if (d < 7) {
        #pragma unroll
        for (int q = 0; q < 4; ++q) {
          f32x2 nx = __builtin_elementwise_fma(t0[q], c0[q], -p0[q]);
          p0[q] = c0[q];
          c0[q] = nx;
        }
      }
    }
  }
  // x(1) + recurrence state for basis(1)
  xa = *(const f32x4*)(xw + 32);
  xb = *(const f32x4*)(xw + 36);
  f32x2 cur[4], prev[4], t2[4];
  init_state(xa, xb, cur, prev, t2);

  bf16x8 af[2][2][2], bfr[2][2][2];   // [parity][mt][chunk] / [parity][chunk][nt]
  // B for step (ic=0, d=0)
  {
    const char* bp0 = bp_lane + (size_t)(wc * 4) * 1024;
    #pragma unroll
    for (int ch = 0; ch < 2; ++ch)
      #pragma unroll
      for (int nt = 0; nt < 2; ++nt)
        bfr[0][ch][nt] = *(const bf16x8*)(bp0 + (nt * 2 + ch) * 1024);
  }
  // make basis(0) visible, then read A(0,0)
  __builtin_amdgcn_sched_barrier(0);
  asm volatile("s_waitcnt lgkmcnt(0)" ::: "memory");
  __builtin_amdgcn_s_barrier();
  __builtin_amdgcn_sched_barrier(0);
  #pragma unroll
  for (int mt = 0; mt < 2; ++mt)
    #pragma unroll
    for (int ch = 0; ch < 2; ++ch)
      af[0][mt][ch] =
          *(const bf16x8*)(abase + (wr * 2 + mt) * 2048 + ch * 1024);

  // ---- main loop: ic = 0..6 (basis(ic+1) distributed over 8 phases) ----
  for (int ic = 0; ic < 7; ++ic) {
    const char* ai   = abase + (ic & 1) * 65536;
    const char* ain  = abase + ((ic + 1) & 1) * 65536;
    char*       wp   = wbase + ((ic + 1) & 1) * 65536;
    const char* bpi  = bp_lane + (size_t)(ic * 16 + wc * 4) * 1024;
    const char* bpin = bp_lane + (size_t)((ic + 1) * 16 + wc * 4) * 1024;

    #pragma unroll
    for (int p = 0; p < 8; ++p) {
      // A-frags for next step
      if (p < 7) {
        #pragma unroll
        for (int mt = 0; mt < 2; ++mt)
          #pragma unroll
          for (int ch = 0; ch < 2; ++ch)
            af[(p + 1) & 1][mt][ch] = *(const bf16x8*)(
                ai + (p + 1) * 8192 + (wr * 2 + mt) * 2048 + ch * 1024);
      } else {
        #pragma unroll
        for (int mt = 0; mt < 2; ++mt)
          #pragma unroll
          for (int ch = 0; ch < 2; ++ch)
            af[0][mt][ch] = *(const bf16x8*)(
                ain + (wr * 2 + mt) * 2048 + ch * 1024);
      }
      // B-frags for next step (1 phase deep, counted vmcnt at use)
      if (p < 7) {
        #pragma unroll
        for (int ch = 0; ch < 2; ++ch)
          #pragma unroll
          for (int nt = 0; nt < 2; ++nt)
            bfr[(p + 1) & 1][ch][nt] = *(const bf16x8*)(
                bpi + (size_t)(p + 1) * 131072 + (nt * 2 + ch) * 1024);
      } else {
        #pragma unroll
        for (int ch = 0; ch < 2; ++ch)
          #pragma unroll
          for (int nt = 0; nt < 2; ++nt)
            bfr[0][ch][nt] =
                *(const bf16x8*)(bpin + (nt * 2 + ch) * 1024);
      }
      // basis degree-slice: write T_{p+1}(ic+1) to slot p, advance
      {
        u32x4 pk;
        #pragma unroll
        for (int q = 0; q < 4; ++q) pk[q] = pack_pair(cur[q]);
        *(u32x4*)(wp + p * 8192) = pk;
        if (p < 7) {
          #pragma unroll
          for (int q = 0; q < 4; ++q) {
            f32x2 nx = __builtin_elementwise_fma(t2[q], cur[q], -prev[q]);
            prev[q] = cur[q];
            cur[q]  = nx;
          }
        }
      }
      if (p == 3 && ic <= 5) {     // x for ic+2 (used at p==7)
        xa = *(const f32x4*)(xw + (ic + 2) * 32);
        xb = *(const f32x4*)(xw + (ic + 2) * 32 + 4);
      }
      if (p == 7 && ic <= 5)       // state for basis(ic+2)
        init_state(xa, xb, cur, prev, t2);

      phase_barrier();

      __builtin_amdgcn_s_setprio(1);
      #pragma unroll
      for (int ch = 0; ch < 2; ++ch)
        #pragma unroll
        for (int mt = 0; mt < 2; ++mt)
          #pragma unroll
          for (int nt = 0; nt < 2; ++nt)
            acc[mt][nt] = __builtin_amdgcn_mfma_f32_32x32x16_bf16(
                af[p & 1][mt][ch], bfr[p & 1][ch][nt], acc[mt][nt], 0, 0, 0);
      __builtin_amdgcn_s_setprio(0);
    }
  }

  // ---- final ic = 7: no basis work, no barriers ----
  {
    const char* ai  = abase + 65536;                       // buf1
    const char* bpi = bp_lane + (size_t)(7 * 16 + wc * 4) * 1024;
    #pragma unroll
    for (int p = 0; p < 8; ++p) {
      if (p < 7) {
        #pragma unroll
        for (int mt = 0; mt < 2; ++mt)
          #pragma unroll
          for (int ch = 0; ch < 2; ++ch)
            af[(p + 1) & 1][mt][ch] = *(const bf16x8*)(
                ai + (p + 1) * 8192 + (wr * 2 + mt) * 2048 + ch * 1024);
        #pragma unroll
        for (int ch = 0; ch < 2; ++ch)
          #pragma unroll
          for (int nt = 0; nt < 2; ++nt)
            bfr[(p + 1) & 1][ch][nt] = *(const bf16x8*)(
                bpi + (size_t)(p + 1) * 131072 + (nt * 2 + ch) * 1024);
      }
      __builtin_amdgcn_s_setprio(1);
      #pragma unroll
      for (int ch = 0; ch < 2; ++ch)
        #pragma unroll
        for (int mt = 0; mt < 2; ++mt)
          #pragma unroll
          for (int nt = 0; nt < 2; ++nt)
            acc[mt][nt] = __builtin_amdgcn_mfma_f32_32x32x16_bf16(
                af[p & 1][mt][ch], bfr[p & 1][ch][nt], acc[mt][nt], 0, 0, 0);
      __builtin_amdgcn_s_setprio(0);
    }
  }

  // epilogue: 32x32 C/D layout col=lane&31, row=(r&3)+8*(r>>2)+4*(lane>>5)
  // [measured m74/m101]
  #pragma unroll
  for (int nt = 0; nt < 2; ++nt) {
    int c = wc * 64 + nt * 32 + (lane & 31);
    float bv = bias[c];
    #pragma unroll
    for (int mt = 0; mt < 2; ++mt) {
      int rbase = base_row + wr * 64 + mt * 32 + 4 * (lane >> 5);
      #pragma unroll
      for (int r = 0; r < 16; ++r) {
        int row = rbase + (r & 3) + 8 * (r >> 2);
        out[(size_t)row * NOUT + c] = acc[mt][nt][r] + bv;
      }
    }
  }
}

extern "C" void kernel_launch(void* const* d_in, const int* in_sizes, int n_in,
                              void* d_out, int out_size, void* d_ws, size_t ws_size,
                              hipStream_t stream) {
  const float* x  = (const float*)d_in[0];
  const float* cb = (const float*)d_in[1];   // c_basis (256,256,9)
  const float* ca = (const float*)d_in[2];   // c_act   (256,256)
  float* out = (float*)d_out;

  unsigned short* Bp = (unsigned short*)d_ws;                    // 1 MB
  float* bias = (float*)((char*)d_ws + 8 * NIN * NOUT * 2);      // 1 KB

  cheby_prepack<<<(8 * NIN * NOUT) / 256, 256, 0, stream>>>(cb, ca, Bp);
  cheby_bias<<<NOUT, 64, 0, stream>>>(cb, ca, bias);
  cheby_mfma<<<256, 512, 0, stream>>>(x, Bp, bias, out);
}

// Round 16
// 45.718 us; speedup vs baseline: 1.1795x; 1.1236x over previous
//
#include <hip/hip_runtime.h>
#include <hip/hip_bf16.h>

// Problem constants
#define BATCH 32768
#define NIN   256
#define NOUT  256
// degrees 1..8 via MFMA; degree 0 (T_0 = 1) folded into per-column bias

typedef __attribute__((ext_vector_type(8))) short bf16x8;
typedef __attribute__((ext_vector_type(4))) float f32x4;
typedef __attribute__((ext_vector_type(2))) float f32x2;
typedef __attribute__((ext_vector_type(4))) unsigned int u32x4;

static __device__ __forceinline__ unsigned short bf16_rne(float f) {
  unsigned u = __float_as_uint(f);
  u += 0x7fffu + ((u >> 16) & 1u);
  return (unsigned short)(u >> 16);
}

// fast tanh: t = sign(v) * (1 - z) / (1 + z), z = exp(-2|v|)
static __device__ __forceinline__ float fast_tanh(float v) {
  float a = fabsf(v);
  float z = __expf(-2.0f * a);
  float r = (1.0f - z) * __builtin_amdgcn_rcpf(1.0f + z);
  return copysignf(r, v);
}

static __device__ __forceinline__ unsigned pack_pair(f32x2 v) {
  __hip_bfloat162 h2 = __float22bfloat162_rn(make_float2(v[0], v[1]));
  union { __hip_bfloat162 h; unsigned u; } cv;
  cv.h = h2;
  return cv.u;
}

static __device__ __forceinline__ void init_state(const f32x4 x0, const f32x4 x1,
                                                  f32x2* cur, f32x2* prev,
                                                  f32x2* t2) {
  #pragma unroll
  for (int p = 0; p < 4; ++p) {
    float va = (p < 2) ? x0[2 * p]     : x1[2 * p - 4];
    float vb = (p < 2) ? x0[2 * p + 1] : x1[2 * p - 3];
    float ta = fast_tanh(va);
    float tb = fast_tanh(vb);
    cur[p]  = (f32x2){ta, tb};        // T_1
    t2[p]   = cur[p] + cur[p];
    prev[p] = (f32x2){1.0f, 1.0f};    // T_0
  }
}

// raw barrier (no vmcnt drain) with scheduler fences
static __device__ __forceinline__ void phase_barrier() {
  __builtin_amdgcn_sched_barrier(0);
  __builtin_amdgcn_s_barrier();
  __builtin_amdgcn_sched_barrier(0);
}

// ---------------------------------------------------------------------------
// Merged prepack + bias (ONE launch instead of two).
// Grid: 256 blocks (one per output column n), 256 threads (one per input i).
// Thread (n,i): loads cb[n][i][0..8] (f32x4+f32x4+scalar) and ca[n][i];
//   - writes 8 prepacked bf16 weights into the MFMA fragment layout:
//       Bp[((dm*8+ic)*16+tile)*512 + kg*128 + col*8 + j],
//       ic=i>>5, kg=(i>>3)&3, j=i&7, tile=n>>4, col=n&15
//   - contributes cb[n][i][0]*ca[n][i] to bias[n] via block reduction.
// ---------------------------------------------------------------------------
__global__ void cheby_prep(const float* __restrict__ cb,
                           const float* __restrict__ ca,
                           unsigned short* __restrict__ Bp,
                           float* __restrict__ bias) {
  __shared__ float red[256];
  int n = blockIdx.x;
  int i = threadIdx.x;

  const float* cp = cb + ((size_t)n * NIN + i) * 9;
  f32x4 c0 = *(const f32x4*)cp;          // cb[..][0..3] (4B aligned; 36B stride)
  f32x4 c1 = *(const f32x4*)(cp + 4);    // cb[..][4..7]
  float c8  = cp[8];
  float av  = ca[(size_t)n * NIN + i];

  int ic   = i >> 5;
  int kg   = (i >> 3) & 3;
  int j    = i & 7;
  int tile = n >> 4;
  int col  = n & 15;
  size_t base = (size_t)kg * 128 + col * 8 + j;
  // element offset for degree dm: ((dm*8+ic)*16+tile)*512 + base
  #pragma unroll
  for (int dm = 0; dm < 8; ++dm) {
    float w = ((dm < 3) ? c0[dm + 1] : (dm < 7) ? c1[dm - 3] : c8) * av;
    Bp[(((size_t)dm * 8 + ic) * 16 + tile) * 512 + base] = bf16_rne(w);
  }

  // bias reduction: sum_i cb[n][i][0]*ca[n][i]
  red[i] = c0[0] * av;
  __syncthreads();
  #pragma unroll
  for (int s = 128; s >= 64; s >>= 1) {
    if (i < s) red[i] += red[i + s];
    __syncthreads();
  }
  if (i < 64) {
    float v = red[i];
    #pragma unroll
    for (int off = 32; off; off >>= 1) v += __shfl_down(v, off);
    if (i == 0) bias[n] = v;
  }
}

// ---------------------------------------------------------------------------
// Fused cheby + GEMM, 8-phase pipelined, 128-row blocks (R10, best verified).
// Grid: 256 blocks x 512 threads (8 waves) -> 1 block/CU, LDS 128KB.
// Block tile: 128 rows x 256 cols. Wave tile: 64x64 (wr=w>>2 row half,
// wc=w&3 col strip). Basis computed exactly once per x element (wave w
// writes plane w). Per phase: { ds_read A(next) || 4 B-loads(next) ||
// basis slice(ic+1) } -> s_barrier -> 16 MFMA.
// ---------------------------------------------------------------------------
__global__ __launch_bounds__(512, 2)
void cheby_mfma(const float* __restrict__ x,
                const unsigned short* __restrict__ Bp,
                const float* __restrict__ bias,
                float* __restrict__ out) {
  // [buf][d-1][plane 0..7][frag: kg*256B + row16*16B] -- 1KB planes, 128KB
  __shared__ unsigned short Asm_[2][8][8][512];

  int tid  = threadIdx.x;
  int w    = tid >> 6;            // 0..7
  int lane = tid & 63;
  int row16 = lane & 15;          // A row / B col / C-D col
  int kg    = lane >> 4;          // k-group 0..3

  int wr = w >> 2;                // row half (0..1)
  int wc = w & 3;                 // col strip (0..3)
  int base_row = blockIdx.x * 128;
  int tile0    = wc * 4;          // wave's 4 column tiles (64 cols)

  // writer role: wave w covers rows w*16..w*16+15 (plane w)
  const float* xw = x + (size_t)(base_row + w * 16 + row16) * NIN + kg * 8;
  char* wbase = (char*)Asm_ + (w * 1024 + lane * 16);  // + d*8192 + buf*65536
  // reader
  const char* abase   = (const char*)Asm_ + lane * 16;
  const char* bp_lane = (const char*)Bp + kg * 256 + row16 * 16;

  f32x4 acc[4][4];
  #pragma unroll
  for (int a = 0; a < 4; ++a)
    #pragma unroll
    for (int b = 0; b < 4; ++b) acc[a][b] = (f32x4)0.0f;

  // ---- prologue: full basis(0) -> buf0 ----
  f32x4 xa = *(const f32x4*)xw;
  f32x4 xb = *(const f32x4*)(xw + 4);
  {
    f32x2 c0[4], p0[4], t0[4];
    init_state(xa, xb, c0, p0, t0);
    #pragma unroll
    for (int d = 1; d <= 8; ++d) {
      u32x4 pk;
      #pragma unroll
      for (int q = 0; q < 4; ++q) pk[q] = pack_pair(c0[q]);
      *(u32x4*)(wbase + (d - 1) * 8192) = pk;
      if (d < 8) {
        #pragma unroll
        for (int q = 0; q < 4; ++q) {
          f32x2 nx = __builtin_elementwise_fma(t0[q], c0[q], -p0[q]);
          p0[q] = c0[q];
          c0[q] = nx;
        }
      }
    }
  }
  // x(1) + recurrence state for basis(1)
  xa = *(const f32x4*)(xw + 32);
  xb = *(const f32x4*)(xw + 36);
  f32x2 cur[4], prev[4], t2[4];
  init_state(xa, xb, cur, prev, t2);

  bf16x8 af[2][4], bfr[2][4];
  // B for step (0,0)
  {
    const char* bp0 = bp_lane + (size_t)tile0 * 1024;
    #pragma unroll
    for (int nt = 0; nt < 4; ++nt)
      bfr[0][nt] = *(const bf16x8*)(bp0 + nt * 1024);
  }
  // make basis(0) visible, then read A(0,0)
  __builtin_amdgcn_sched_barrier(0);
  asm volatile("s_waitcnt lgkmcnt(0)" ::: "memory");
  __builtin_amdgcn_s_barrier();
  __builtin_amdgcn_sched_barrier(0);
  #pragma unroll
  for (int mt = 0; mt < 4; ++mt)
    af[0][mt] = *(const bf16x8*)(abase + (wr * 4 + mt) * 1024);

  // ---- main loop: ic = 0..6 (basis for ic+1 distributed over 8 phases) ----
  for (int ic = 0; ic < 7; ++ic) {
    const char* ai   = abase + (ic & 1) * 65536 + (wr * 4) * 1024;
    const char* ain  = abase + ((ic + 1) & 1) * 65536 + (wr * 4) * 1024;
    char*       wp   = wbase + ((ic + 1) & 1) * 65536;
    const char* bpi  = bp_lane + (size_t)(ic * 16 + tile0) * 1024;
    const char* bpin = bp_lane + (size_t)((ic + 1) * 16 + tile0) * 1024;

    #pragma unroll
    for (int p = 0; p < 8; ++p) {
      // A-frags for next step
      if (p < 7) {
        #pragma unroll
        for (int mt = 0; mt < 4; ++mt)
          af[(p + 1) & 1][mt] =
              *(const bf16x8*)(ai + (p + 1) * 8192 + mt * 1024);
      } else {
        #pragma unroll
        for (int mt = 0; mt < 4; ++mt)
          af[0][mt] = *(const bf16x8*)(ain + mt * 1024);
      }
      // B-frags for next step (1 phase deep, counted vmcnt at use)
      if (p < 7) {
        #pragma unroll
        for (int nt = 0; nt < 4; ++nt)
          bfr[(p + 1) & 1][nt] =
              *(const bf16x8*)(bpi + (size_t)(p + 1) * 131072 + nt * 1024);
      } else {
        #pragma unroll
        for (int nt = 0; nt < 4; ++nt)
          bfr[0][nt] = *(const bf16x8*)(bpin + nt * 1024);
      }
      // basis degree-slice: write T_{p+1}(ic+1), advance recurrence
      {
        u32x4 pk;
        #pragma unroll
        for (int q = 0; q < 4; ++q) pk[q] = pack_pair(cur[q]);
        *(u32x4*)(wp + p * 8192) = pk;
        if (p < 7) {
          #pragma unroll
          for (int q = 0; q < 4; ++q) {
            f32x2 nx = __builtin_elementwise_fma(t2[q], cur[q], -prev[q]);
            prev[q] = cur[q];
            cur[q]  = nx;
          }
        }
      }
      if (p == 3 && ic <= 5) {     // x for ic+2 (used at p==7)
        xa = *(const f32x4*)(xw + (ic + 2) * 32);
        xb = *(const f32x4*)(xw + (ic + 2) * 32 + 4);
      }
      if (p == 7 && ic <= 5)       // state for basis(ic+2)
        init_state(xa, xb, cur, prev, t2);

      phase_barrier();

      __builtin_amdgcn_s_setprio(1);
      #pragma unroll
      for (int mt = 0; mt < 4; ++mt)
        #pragma unroll
        for (int nt = 0; nt < 4; ++nt)
          acc[mt][nt] = __builtin_amdgcn_mfma_f32_16x16x32_bf16(
              af[p & 1][mt], bfr[p & 1][nt], acc[mt][nt], 0, 0, 0);
      __builtin_amdgcn_s_setprio(0);
    }
  }

  // ---- final ic = 7: no basis work, no barriers ----
  {
    const char* ai  = abase + 65536 + (wr * 4) * 1024;   // buf1
    const char* bpi = bp_lane + (size_t)(7 * 16 + tile0) * 1024;
    #pragma unroll
    for (int p = 0; p < 8; ++p) {
      if (p < 7) {
        #pragma unroll
        for (int mt = 0; mt < 4; ++mt)
          af[(p + 1) & 1][mt] =
              *(const bf16x8*)(ai + (p + 1) * 8192 + mt * 1024);
        #pragma unroll
        for (int nt = 0; nt < 4; ++nt)
          bfr[(p + 1) & 1][nt] =
              *(const bf16x8*)(bpi + (size_t)(p + 1) * 131072 + nt * 1024);
      }
      __builtin_amdgcn_s_setprio(1);
      #pragma unroll
      for (int mt = 0; mt < 4; ++mt)
        #pragma unroll
        for (int nt = 0; nt < 4; ++nt)
          acc[mt][nt] = __builtin_amdgcn_mfma_f32_16x16x32_bf16(
              af[p & 1][mt], bfr[p & 1][nt], acc[mt][nt], 0, 0, 0);
      __builtin_amdgcn_s_setprio(0);
    }
  }

  // epilogue: C/D layout col = lane&15, row = (lane>>4)*4 + q  (m89/m91)
  #pragma unroll
  for (int nt = 0; nt < 4; ++nt) {
    int c = (tile0 + nt) * 16 + row16;
    float bv = bias[c];
    #pragma unroll
    for (int mt = 0; mt < 4; ++mt) {
      int r0 = base_row + wr * 64 + mt * 16 + kg * 4;
      #pragma unroll
      for (int q = 0; q < 4; ++q)
        out[(size_t)(r0 + q) * NOUT + c] = acc[mt][nt][q] + bv;
    }
  }
}

extern "C" void kernel_launch(void* const* d_in, const int* in_sizes, int n_in,
                              void* d_out, int out_size, void* d_ws, size_t ws_size,
                              hipStream_t stream) {
  const float* x  = (const float*)d_in[0];
  const float* cb = (const float*)d_in[1];   // c_basis (256,256,9)
  const float* ca = (const float*)d_in[2];   // c_act   (256,256)
  float* out = (float*)d_out;

  unsigned short* Bp = (unsigned short*)d_ws;                    // 1 MB
  float* bias = (float*)((char*)d_ws + 8 * NIN * NOUT * 2);      // 1 KB

  cheby_prep<<<NOUT, 256, 0, stream>>>(cb, ca, Bp, bias);
  cheby_mfma<<<256, 512, 0, stream>>>(x, Bp, bias, out);
}